// Round 23
// baseline (203.311 us; speedup 1.0000x reference)
//
#include <hip/hip_runtime.h>
#include <math.h>

#define NT 512           // 8 waves
#define MB 32            // queries per block (4 buffers -> 32 KB LDS -> 4 blocks/CU)
#define NB 4096
#define MTOT 131072
#define IMG_H 384
#define IMG_W 512
#define H8 48
#define W8 64
#define H16 24
#define W16 32

#define SPE 40           // pe row stride (u16), global scratch

typedef _Float16 half8_t __attribute__((ext_vector_type(8)));
typedef _Float16 half4_t __attribute__((ext_vector_type(4)));
typedef float f32x4_t __attribute__((ext_vector_type(4)));
typedef unsigned short u16;

// LDS swizzle: 16B-group index gi (0..15) of row r maps to gi ^ (r & 7).
#define SWZ(r, gi) ((gi) ^ ((r) & 7))

// packed weight fragment order: ((nt*KT + kt)*64 + lane)*8 + j
// element = W[kt*32 + (lane>>4)*8 + j][nt*16 + (lane&15)]
#define PW_PP1    0
#define PW_MEGA1  12288
#define PW_S8     77824
#define PW_MEGA2  110592
#define PW_S15    176128
#define PW_HW1    208896
#define PW_HW2    229376
#define PW_END    237568
#define FT8_OFF   PW_END
#define FT8_CNT   (2*H8*W8*128)
#define FT16_OFF  (FT8_OFF + FT8_CNT)
#define FT16_CNT  (2*H16*W16*128)
#define F32_OFF   (FT16_OFF + FT16_CNT)   // f32 region: bA[0,256) bB[256,512)
#define PEG_OFF   (F32_OFF + 2*512)       // u16 [NB][32][40]
#define PEG_CNT   (NB*MB*SPE)
#define CBG_OFF   (PEG_OFF + PEG_CNT)     // f32 [NB][32][2]

__device__ __forceinline__ u16 tohalf(float v) {
  return __builtin_bit_cast(u16, (_Float16)v);
}
// tanh-form gelu; |err vs exact erf-gelu| < 3e-3
__device__ __forceinline__ float geluf(float x) {
  float x2 = x * x;
  float t = x * fmaf(x2, 0.0713548162726f, 1.5957691216057308f);
  float e = __expf(-t);
  return x * __builtin_amdgcn_rcpf(1.0f + e);
}

__device__ __forceinline__ float bilin_plane(const float* __restrict__ plane,
                                             int Wd, int Hd, float x, float y) {
  x = fminf(fmaxf(x, 0.f), (float)(Wd - 1));
  y = fminf(fmaxf(y, 0.f), (float)(Hd - 1));
  float x0f = floorf(x), y0f = floorf(y);
  int x0 = (int)x0f, y0 = (int)y0f;
  int x1 = min(x0 + 1, Wd - 1), y1 = min(y0 + 1, Hd - 1);
  float wx = x - x0f, wy = y - y0f;
  const float* r0 = plane + y0 * Wd;
  const float* r1 = plane + y1 * Wd;
  float v00 = r0[x0], v01 = r0[x1], v10 = r1[x0], v11 = r1[x1];
  float top = v00 + wx * (v01 - v00);
  float bot = v10 + wx * (v11 - v10);
  return top + wy * (bot - top);
}

// bilinear gather of 8 fp16 channels, packed-f16 interpolation.
__device__ __forceinline__ void featSample(const u16* __restrict__ ft, int Wd, int Hd,
                                           float x, float y, u16* dstRow,
                                           int i16, int giS) {
  x = fminf(fmaxf(x, 0.f), (float)(Wd - 1));
  y = fminf(fmaxf(y, 0.f), (float)(Hd - 1));
  float x0f = floorf(x), y0f = floorf(y);
  int x0 = (int)x0f, y0 = (int)y0f;
  int x1 = min(x0 + 1, Wd - 1), y1 = min(y0 + 1, Hd - 1);
  _Float16 wx = (_Float16)(x - x0f), wy = (_Float16)(y - y0f);
  half8_t v00 = *reinterpret_cast<const half8_t*>(ft + (y0 * Wd + x0) * 128 + i16 * 8);
  half8_t v01 = *reinterpret_cast<const half8_t*>(ft + (y0 * Wd + x1) * 128 + i16 * 8);
  half8_t v10 = *reinterpret_cast<const half8_t*>(ft + (y1 * Wd + x0) * 128 + i16 * 8);
  half8_t v11 = *reinterpret_cast<const half8_t*>(ft + (y1 * Wd + x1) * 128 + i16 * 8);
  half8_t top = v00 + wx * (v01 - v00);
  half8_t bot = v10 + wx * (v11 - v10);
  half8_t r = top + wy * (bot - top);
  *reinterpret_cast<half8_t*>(dstRow + giS * 8) = r;
}

// 32-row x 128-col matvec slice via MFMA 16x16x32 fp16, 8 waves split N (nt=w),
// 2 row-fragments per wave. Swizzled LDS sources; SWB=0 -> plain aB (peg).
template <int KT, int SPLITKT, int ACT, int SWB = 1, int NWAVES = 8>
__device__ __forceinline__ void mmv(
    const u16* __restrict__ wpk,
    const u16* aA, const u16* aB, int strB,
    const float* __restrict__ bias,
    u16* ob) {
  const int tid = threadIdx.x;
  const int lane = tid & 63;
  const int w = tid >> 6;
  const int l15 = lane & 15;
  const int g = lane >> 4;
  if (NWAVES == 8 || w < NWAVES) {
    f32x4_t acc[2];
#pragma unroll
    for (int mt = 0; mt < 2; ++mt) acc[mt] = (f32x4_t){0.f, 0.f, 0.f, 0.f};
    __builtin_amdgcn_s_setprio(1);
#pragma unroll
    for (int kt = 0; kt < KT; ++kt) {
      half8_t af[2];
#pragma unroll
      for (int mt = 0; mt < 2; ++mt) {
        const int row = mt * 16 + l15;
        const u16* p;
        if (kt < SPLITKT) {
          p = aA + row * 128 + SWZ(row, kt * 4 + g) * 8;
        } else if (SWB) {
          p = aB + row * 128 + SWZ(row, (kt - SPLITKT) * 4 + g) * 8;
        } else {
          p = aB + row * strB + (kt - SPLITKT) * 32 + g * 8;
        }
        af[mt] = *reinterpret_cast<const half8_t*>(p);
      }
      half8_t bf = *reinterpret_cast<const half8_t*>(wpk + ((w * KT + kt) * 64 + lane) * 8);
#pragma unroll
      for (int mt = 0; mt < 2; ++mt)
        acc[mt] = __builtin_amdgcn_mfma_f32_16x16x32_f16(bf, af[mt], acc[mt], 0, 0, 0);
    }
    __builtin_amdgcn_s_setprio(0);
    const int c0 = (w << 4) + (g << 2);   // 4-aligned output column
    f32x4_t bv = *reinterpret_cast<const f32x4_t*>(bias + c0);
#pragma unroll
    for (int mt = 0; mt < 2; ++mt) {
      const int row = (mt << 4) + l15;
      half4_t hv;
#pragma unroll
      for (int r = 0; r < 4; ++r) {
        float v = acc[mt][r] + bv[r];
        if (ACT == 1) v = geluf(v);
        hv[r] = (_Float16)v;
      }
      const int e = row * 128 + (c0 ^ ((row & 7) << 3));
      *reinterpret_cast<half4_t*>(ob + e) = hv;
    }
  }
}

// layernorm rows of src [32][128](swz) -> dst [32][128](swz), 8 threads/row
__device__ __forceinline__ void lnorm(const u16* src, u16* dst,
                                      const float* __restrict__ lw,
                                      const float* __restrict__ lb) {
  const int tid = threadIdx.x;
  if (tid < 8 * MB) {
    int q = tid >> 3, s = tid & 7;
    float xs[16];
    float sum = 0.f, sum2 = 0.f;
#pragma unroll
    for (int c8 = 0; c8 < 2; ++c8) {
      const int gi = SWZ(q, 2 * s + c8);
      half8_t v = *reinterpret_cast<const half8_t*>(src + q * 128 + gi * 8);
#pragma unroll
      for (int j = 0; j < 8; ++j) {
        float x = (float)v[j];
        xs[c8 * 8 + j] = x; sum += x; sum2 += x * x;
      }
    }
    sum += __shfl_xor(sum, 1); sum2 += __shfl_xor(sum2, 1);
    sum += __shfl_xor(sum, 2); sum2 += __shfl_xor(sum2, 2);
    sum += __shfl_xor(sum, 4); sum2 += __shfl_xor(sum2, 4);
    float mean = sum * 0.0078125f;
    float var = sum2 * 0.0078125f - mean * mean;
    float rstd = rsqrtf(var + 1e-5f);
#pragma unroll
    for (int c8 = 0; c8 < 2; ++c8) {
      half8_t r;
#pragma unroll
      for (int j = 0; j < 8; ++j) {
        int c = s * 16 + c8 * 8 + j;
        r[j] = (_Float16)((xs[c8 * 8 + j] - mean) * rstd * lw[c] + lb[c]);
      }
      const int gi = SWZ(q, 2 * s + c8);
      *reinterpret_cast<half8_t*>(dst + q * 128 + gi * 8) = r;
    }
  }
}

// ---------------- single prep kernel (identical to r22) ----------------
struct PrepAllArgs {
  const float *pp_w1, *pp_w2, *p8_w, *p16_w, *f1_ph_w, *f1_gate, *f1_w1, *f1_w2;
  const float *f2_ph_w, *f2_gate, *f2_w1, *f2_w2, *h_w1, *h_w2;
  const float *p8_b, *f1_ph_b, *pp_b2, *f1_b1, *p16_b, *f2_ph_b, *f2_b1;
  const float *feat8, *feat16;
  u16 *dst;
  float *bA, *bB;
  u16 *ft8, *ft16;
};

__global__ void prep_all(PrepAllArgs a) {
  __shared__ float lds[256];
  const int blk = blockIdx.x;
  const int tid = threadIdx.x;
  if (blk < 512) {
    const int sec = blk >> 8;      // 0: MEGA1, 1: MEGA2
    const int k = blk & 255;
    float* Arow = lds;             // [128]
    if (sec == 0) {
      if (k < 128) {
        if (tid < 128) Arow[tid] = a.p8_w[k * 128 + tid];
      } else {
        float* prow = lds + 128;
        if (tid < 128) prow[tid] = a.pp_w2[(k - 128) * 128 + tid];
        __syncthreads();
        if (tid < 128) {
          float sig = __builtin_amdgcn_rcpf(1.f + __expf(-a.f1_gate[tid]));
          float acc = 0.f;
          for (int r = 0; r < 128; ++r) acc += prow[r] * a.f1_ph_w[r * 128 + tid];
          Arow[tid] = acc * sig;
        }
      }
    } else {
      if (k < 128) {
        if (tid < 128) Arow[tid] = a.p16_w[k * 128 + tid];
      } else {
        if (tid < 128) {
          float sig = __builtin_amdgcn_rcpf(1.f + __expf(-a.f2_gate[tid]));
          Arow[tid] = a.f2_ph_w[(k - 128) * 128 + tid] * sig;
        }
      }
    }
    __syncthreads();
    const float* W1 = (sec == 0) ? a.f1_w1 : a.f2_w1;
    float acc = 0.f;
    for (int m = 0; m < 128; ++m) acc += Arow[m] * W1[m * 256 + tid];
    const int kt = k >> 5, hi = (k >> 3) & 3, j = k & 7;
    const int nt = tid >> 4, lo = tid & 15;
    const int base = (sec == 0) ? PW_MEGA1 : PW_MEGA2;
    a.dst[base + (((nt * 8 + kt) * 64 + hi * 16 + lo) << 3) + j] = tohalf(acc);
  } else if (blk == 512) {
    float* u = lds;
    if (tid < 128) {
      float sig = __builtin_amdgcn_rcpf(1.f + __expf(-a.f1_gate[tid]));
      float acc = 0.f;
      for (int r = 0; r < 128; ++r) acc += a.pp_b2[r] * a.f1_ph_w[r * 128 + tid];
      u[tid] = a.p8_b[tid] + sig * a.f1_ph_b[tid] + sig * acc;
    }
    __syncthreads();
    float acc = a.f1_b1[tid];
    for (int m = 0; m < 128; ++m) acc += u[m] * a.f1_w1[m * 256 + tid];
    a.bA[tid] = acc;
  } else if (blk == 513) {
    float acc = a.f2_b1[tid];
    for (int m = 0; m < 128; ++m) {
      float sig = __builtin_amdgcn_rcpf(1.f + __expf(-a.f2_gate[m]));
      acc += (a.p16_b[m] + sig * a.f2_ph_b[m]) * a.f2_w1[m * 256 + tid];
    }
    a.bB[tid] = acc;
  } else if (blk < 930) {
    const int vi = (blk - 514) * 256 + tid;
    const int vb[6] = {0, 12288, 45056, 77824, 98304, 106496};
    const int KTs[5] = {3, 8, 8, 5, 4};
    const int Ks[5]  = {75, 256, 256, 156, 128};
    const int Ns[5]  = {128, 128, 128, 128, 64};
    const int pw[5]  = {PW_PP1, PW_S8, PW_S15, PW_HW1, PW_HW2};
    int s = 0;
    while (vi >= vb[s + 1]) ++s;
    const int rem = vi - vb[s];
    const int e = rem & 511, lane = e >> 3, j = e & 7;
    const int ntkt = rem >> 9;
    const int kt = ntkt % KTs[s], nt = ntkt / KTs[s];
    const int k = kt * 32 + ((lane >> 4) << 3) + j;
    const int col = (nt << 4) + (lane & 15);
    const float* src = (s == 0) ? a.pp_w1 : (s == 1) ? a.f1_w2
                     : (s == 2) ? a.f2_w2 : (s == 3) ? a.h_w1 : a.h_w2;
    float v = (k < Ks[s]) ? src[k * Ns[s] + col] : 0.f;
    a.dst[pw[s] + rem] = tohalf(v);
  } else {
    const int tot8 = 2 * 128 * H8 * W8;
    const int i = (blk - 930) * 256 + tid;
    if (i < tot8) {
      int x = i % W8;
      int t = i / W8;
      int y = t % H8; t /= H8;
      int c = t % 128;
      int b = t / 128;
      a.ft8[((b * H8 + y) * W8 + x) * 128 + c] = tohalf(a.feat8[i]);
    } else {
      int i2 = i - tot8;
      int x = i2 % W16;
      int t = i2 / W16;
      int y = t % H16; t /= H16;
      int c = t % 128;
      int b = t / 128;
      a.ft16[((b * H16 + y) * W16 + x) * 128 + c] = tohalf(a.feat16[i2]);
    }
  }
}

// ---------------- main fused kernel (11 phases, MB=32, 32KB LDS) ------------
struct KParams {
  const float *img, *coarse_flow, *qc;
  const u16 *wpk, *ft8, *ft16;
  const float *bA, *bB;
  u16* peg;
  float* cbg;
  const float *pp_b1;
  const float *f1_b2, *f1_ln_w, *f1_ln_b;
  const float *f2_b2, *f2_ln_w, *f2_ln_b;
  const float *h_b1, *h_b2, *h_w3, *h_b3;
  float* out;
};

__global__ __launch_bounds__(NT, 2) void ifd_mfma(KParams P) {
  __shared__ __align__(16) u16 smem[4 * MB * 128];   // 32768 B -> 4 blocks/CU
  u16* ab0 = smem;
  u16* ab1 = smem + MB * 128;
  u16* tb  = smem + 2 * MB * 128;
  u16* hb  = smem + 3 * MB * 128;

  const int tid = threadIdx.x;
  const int m0 = blockIdx.x * MB;
  u16* pegB = P.peg + blockIdx.x * (MB * SPE);
  float* cbgB = P.cbg + blockIdx.x * (MB * 2);

  // ---- Ph1: patches -> ab0[0..95](swz) (tid<256); pe (256..319); coarse
  //      (320..383); zero-pad (384..447) ----
  if (tid < 8 * MB) {
    const int q = tid >> 3, sub = tid & 7;
    const int m = m0 + q, b = m >> 16;
    const float qx = P.qc[2 * m], qy = P.qc[2 * m + 1];
    const float* imgb = P.img + b * 3 * (IMG_H * IMG_W);
#pragma unroll
    for (int j = 0; j < 12; ++j) {
      const int c = sub * 12 + j;
      u16 val = 0;
      if (c < 75) {
        int p = c / 3, ch = c - p * 3;
        int iy = p / 5, ix = p - iy * 5;
        val = tohalf(bilin_plane(imgb + ch * (IMG_H * IMG_W), IMG_W, IMG_H,
                                 qx + (float)(ix - 2), qy + (float)(iy - 2)));
      }
      ab0[q * 128 + (c ^ ((q & 7) << 3))] = val;
    }
  } else if (tid < 8 * MB + 2 * MB) {        // pe via angle doubling
    const int t2 = tid - 8 * MB, q = t2 >> 1, dim = t2 & 1;
    const int m = m0 + q;
    const float qv = P.qc[2 * m + dim];
    const float q8 = qv * 0.125f;
    const float loc = (q8 - rintf(q8)) * 2.f;
    pegB[q * SPE + dim] = tohalf(loc);
    const float th = loc * 3.14159265358979323846f;
    float s = __sinf(th), c = __cosf(th);
    const int base = q * SPE + 2 + dim * 12;
#pragma unroll
    for (int bnd = 0; bnd < 6; ++bnd) {
      pegB[base + bnd] = tohalf(s);
      pegB[base + 6 + bnd] = tohalf(c);
      float s2 = 2.f * s * c;
      c = fmaf(-2.f * s, s, 1.f);
      s = s2;
    }
  } else if (tid < 8 * MB + 4 * MB) {        // coarse
    const int t2 = tid - 8 * MB - 2 * MB, q = t2 >> 1, o = t2 & 1;
    const int m = m0 + q, b = m >> 16;
    const float qx = P.qc[2 * m], qy = P.qc[2 * m + 1];
    const float x8 = qx * (63.f / 511.f), y8 = qy * (47.f / 383.f);
    const float cv = 8.f * bilin_plane(P.coarse_flow + (b * 2 + o) * (H8 * W8),
                                       W8, H8, x8, y8);
    pegB[q * SPE + 26 + o] = tohalf(cv);
    cbgB[q * 2 + o] = cv;
  } else if (tid < 8 * MB + 6 * MB) {        // zero peg cols 28..31
    const int t2 = tid - 8 * MB - 4 * MB, q = t2 >> 1, pr = t2 & 1;
    *reinterpret_cast<unsigned int*>(pegB + q * SPE + 28 + 2 * pr) = 0u;
  }
  __syncthreads();

  // ---- Ph2: S1 (ab0 -> ab1) || samp8 -> hb ----
  mmv<3, 3, 1>(P.wpk + PW_PP1, ab0, ab0, 128, P.pp_b1, ab1);
  for (int i = tid; i < MB * 16; i += NT) {
    int q = i >> 4, i16 = i & 15;
    int m = m0 + q, b = m >> 16;
    float x = P.qc[2 * m] * (63.f / 511.f), y = P.qc[2 * m + 1] * (47.f / 383.f);
    featSample(P.ft8 + b * (H8 * W8 * 128), W8, H8, x, y, hb + q * 128,
               i16, SWZ(q, i16));
  }
  __syncthreads();

  // ---- Ph3: MEGA1: wide = gelu([samp8(hb) | t1(ab1)] @ WA + bA) -> [ab0 | tb] ----
  mmv<8, 4, 1>(P.wpk + PW_MEGA1, hb, ab1, 128, P.bA, ab0);
  mmv<8, 4, 1>(P.wpk + PW_MEGA1 + 32768, hb, ab1, 128, P.bA + 128, tb);
  __syncthreads();

  // ---- Ph4: S8: [ab0 | tb] @ f1_w2 + f1_b2 -> ab1 ----
  mmv<8, 4, 0>(P.wpk + PW_S8, ab0, tb, 128, P.f1_b2, ab1);
  __syncthreads();

  // ---- Ph5: LN1 (ab1 -> hb) || samp16 -> ab0 ----
  lnorm(ab1, hb, P.f1_ln_w, P.f1_ln_b);
  for (int i = tid; i < MB * 16; i += NT) {
    int q = i >> 4, i16 = i & 15;
    int m = m0 + q, b = m >> 16;
    float x = P.qc[2 * m] * (31.f / 511.f), y = P.qc[2 * m + 1] * (23.f / 383.f);
    featSample(P.ft16 + b * (H16 * W16 * 128), W16, H16, x, y, ab0 + q * 128,
               i16, SWZ(q, i16));
  }
  __syncthreads();

  // ---- Ph6: MEGA2: wide2 = gelu([samp16(ab0) | h2(hb)] @ WB + bB) -> [ab1 | tb] ----
  mmv<8, 4, 1>(P.wpk + PW_MEGA2, ab0, hb, 128, P.bB, ab1);
  mmv<8, 4, 1>(P.wpk + PW_MEGA2 + 32768, ab0, hb, 128, P.bB + 128, tb);
  __syncthreads();

  // ---- Ph7: S15: [ab1 | tb] @ f2_w2 + f2_b2 -> ab0 ----
  mmv<8, 4, 0>(P.wpk + PW_S15, ab1, tb, 128, P.f2_b2, ab0);
  __syncthreads();

  // ---- Ph8: LN2: ab0 -> hb ----
  lnorm(ab0, hb, P.f2_ln_w, P.f2_ln_b);
  __syncthreads();

  // ---- Ph9: S18: gelu([hb | peg] @ h_w1 + h_b1) -> ab1  (K=160, peg unswizzled) ----
  mmv<5, 4, 1, 0>(P.wpk + PW_HW1, hb, pegB, SPE, P.h_b1, ab1);
  __syncthreads();

  // ---- Ph10: S19: gelu(ab1 @ h_w2 + h_b2) -> ab0[0..63]  (waves 0-3) ----
  mmv<4, 4, 1, 1, 4>(P.wpk + PW_HW2, ab1, ab1, 128, P.h_b2, ab0);
  __syncthreads();

  // ---- Ph11: S20: out = coarse + (g @ h_w3 + h_b3) ----
  if (tid < 2 * MB) {
    int q = tid >> 1, o = tid & 1;
    float acc = P.h_b3[o];
    const u16* rp = ab0 + q * 128;
#pragma unroll
    for (int c8 = 0; c8 < 8; ++c8) {
      half8_t v = *reinterpret_cast<const half8_t*>(rp + SWZ(q, c8) * 8);
#pragma unroll
      for (int j = 0; j < 8; ++j) acc += (float)v[j] * P.h_w3[(c8 * 8 + j) * 2 + o];
    }
    P.out[(m0 + q) * 2 + o] = cbgB[q * 2 + o] + acc;
  }
}

extern "C" void kernel_launch(void* const* d_in, const int* in_sizes, int n_in,
                              void* d_out, int out_size, void* d_ws, size_t ws_size,
                              hipStream_t stream) {
  u16* wp = (u16*)d_ws;
  float* fbase = (float*)(wp + F32_OFF);
  float* bA = fbase;
  float* bB = fbase + 256;
  u16* peg = wp + PEG_OFF;
  float* cbg = (float*)(wp + CBG_OFF);

  PrepAllArgs pra;
  pra.pp_w1 = (const float*)d_in[5];
  pra.pp_w2 = (const float*)d_in[7];
  pra.p8_w  = (const float*)d_in[9];
  pra.p16_w = (const float*)d_in[11];
  pra.f1_ph_w = (const float*)d_in[13];
  pra.f1_gate = (const float*)d_in[15];
  pra.f1_w1 = (const float*)d_in[16];
  pra.f1_w2 = (const float*)d_in[18];
  pra.f2_ph_w = (const float*)d_in[22];
  pra.f2_gate = (const float*)d_in[24];
  pra.f2_w1 = (const float*)d_in[25];
  pra.f2_w2 = (const float*)d_in[27];
  pra.h_w1  = (const float*)d_in[31];
  pra.h_w2  = (const float*)d_in[33];
  pra.p8_b  = (const float*)d_in[10];
  pra.f1_ph_b = (const float*)d_in[14];
  pra.pp_b2 = (const float*)d_in[8];
  pra.f1_b1 = (const float*)d_in[17];
  pra.p16_b = (const float*)d_in[12];
  pra.f2_ph_b = (const float*)d_in[23];
  pra.f2_b1 = (const float*)d_in[26];
  pra.feat8 = (const float*)d_in[1];
  pra.feat16 = (const float*)d_in[2];
  pra.dst = wp;
  pra.bA = bA; pra.bB = bB;
  pra.ft8 = wp + FT8_OFF;
  pra.ft16 = wp + FT16_OFF;
  prep_all<<<4770, 256, 0, stream>>>(pra);

  KParams P;
  P.img = (const float*)d_in[0];
  P.coarse_flow = (const float*)d_in[3];
  P.qc = (const float*)d_in[4];
  P.wpk = wp; P.ft8 = wp + FT8_OFF; P.ft16 = wp + FT16_OFF;
  P.bA = bA; P.bB = bB;
  P.peg = peg; P.cbg = cbg;
  P.pp_b1 = (const float*)d_in[6];
  P.f1_b2 = (const float*)d_in[19];
  P.f1_ln_w = (const float*)d_in[20]; P.f1_ln_b = (const float*)d_in[21];
  P.f2_b2 = (const float*)d_in[28];
  P.f2_ln_w = (const float*)d_in[29]; P.f2_ln_b = (const float*)d_in[30];
  P.h_b1 = (const float*)d_in[32]; P.h_b2 = (const float*)d_in[34];
  P.h_w3 = (const float*)d_in[35]; P.h_b3 = (const float*)d_in[36];
  P.out = (float*)d_out;

  ifd_mfma<<<NB, NT, 0, stream>>>(P);
}

// Round 24
// 169.005 us; speedup vs baseline: 1.2030x; 1.2030x over previous
//
#include <hip/hip_runtime.h>
#include <math.h>

#define NT 512           // 8 waves
#define MB 64            // queries per block
#define MTOT 131072
#define IMG_H 384
#define IMG_W 512
#define H8 48
#define W8 64
#define H16 24
#define W16 32

#define SAB 128          // LDS row stride (u16) -- XOR-swizzled layout
#define SPE 40           // pe row stride (u16), global scratch

typedef _Float16 half8_t __attribute__((ext_vector_type(8)));
typedef _Float16 half4_t __attribute__((ext_vector_type(4)));
typedef float f32x4_t __attribute__((ext_vector_type(4)));
typedef unsigned short u16;

// LDS swizzle: 16B-group index gi (0..15) of row r maps to gi ^ (r & 7).
#define SWZ(r, gi) ((gi) ^ ((r) & 7))

// packed weight fragment order: ((nt*KT + kt)*64 + lane)*8 + j
// element = W[kt*32 + (lane>>4)*8 + j][nt*16 + (lane&15)]
// sections: PP1 | MEGA1(WA 256x256) | S8(f1_w2) | MEGA2(WB) | S15(f2_w2) | HW1 | HW2
#define PW_PP1    0
#define PW_MEGA1  12288
#define PW_S8     77824
#define PW_MEGA2  110592
#define PW_S15    176128
#define PW_HW1    208896
#define PW_HW2    229376
#define PW_END    237568
#define FT8_OFF   PW_END
#define FT8_CNT   (2*H8*W8*128)
#define FT16_OFF  (FT8_OFF + FT8_CNT)
#define FT16_CNT  (2*H16*W16*128)
#define F32_OFF   (FT16_OFF + FT16_CNT)   // f32 region: bA[0,256) bB[256,512)
#define PEG_OFF   (F32_OFF + 2*512)       // u16 [2048][64][40]
#define PEG_CNT   (2048*MB*SPE)
#define CBG_OFF   (PEG_OFF + PEG_CNT)     // f32 [2048][64][2]

__device__ __forceinline__ u16 tohalf(float v) {
  return __builtin_bit_cast(u16, (_Float16)v);
}
// tanh-form gelu; |err vs exact erf-gelu| < 3e-3
__device__ __forceinline__ float geluf(float x) {
  float x2 = x * x;
  float t = x * fmaf(x2, 0.0713548162726f, 1.5957691216057308f);
  float e = __expf(-t);
  return x * __builtin_amdgcn_rcpf(1.0f + e);
}

__device__ __forceinline__ float bilin_plane(const float* __restrict__ plane,
                                             int Wd, int Hd, float x, float y) {
  x = fminf(fmaxf(x, 0.f), (float)(Wd - 1));
  y = fminf(fmaxf(y, 0.f), (float)(Hd - 1));
  float x0f = floorf(x), y0f = floorf(y);
  int x0 = (int)x0f, y0 = (int)y0f;
  int x1 = min(x0 + 1, Wd - 1), y1 = min(y0 + 1, Hd - 1);
  float wx = x - x0f, wy = y - y0f;
  const float* r0 = plane + y0 * Wd;
  const float* r1 = plane + y1 * Wd;
  float v00 = r0[x0], v01 = r0[x1], v10 = r1[x0], v11 = r1[x1];
  float top = v00 + wx * (v01 - v00);
  float bot = v10 + wx * (v11 - v10);
  return top + wy * (bot - top);
}

// bilinear gather of 8 fp16 channels, packed-f16 interpolation.
__device__ __forceinline__ void featSample(const u16* __restrict__ ft, int Wd, int Hd,
                                           float x, float y, u16* dstRow,
                                           int i16, int giS) {
  x = fminf(fmaxf(x, 0.f), (float)(Wd - 1));
  y = fminf(fmaxf(y, 0.f), (float)(Hd - 1));
  float x0f = floorf(x), y0f = floorf(y);
  int x0 = (int)x0f, y0 = (int)y0f;
  int x1 = min(x0 + 1, Wd - 1), y1 = min(y0 + 1, Hd - 1);
  _Float16 wx = (_Float16)(x - x0f), wy = (_Float16)(y - y0f);
  half8_t v00 = *reinterpret_cast<const half8_t*>(ft + (y0 * Wd + x0) * 128 + i16 * 8);
  half8_t v01 = *reinterpret_cast<const half8_t*>(ft + (y0 * Wd + x1) * 128 + i16 * 8);
  half8_t v10 = *reinterpret_cast<const half8_t*>(ft + (y1 * Wd + x0) * 128 + i16 * 8);
  half8_t v11 = *reinterpret_cast<const half8_t*>(ft + (y1 * Wd + x1) * 128 + i16 * 8);
  half8_t top = v00 + wx * (v01 - v00);
  half8_t bot = v10 + wx * (v11 - v10);
  half8_t r = top + wy * (bot - top);
  *reinterpret_cast<half8_t*>(dstRow + giS * 8) = r;
}

// 64-row x 128-col matvec slice via MFMA 16x16x32 fp16, 8 waves split N (nt=w),
// 4 row-fragments per wave. Swizzled LDS sources; SWB=0 -> plain aB (peg).
template <int KT, int SPLITKT, int ACT, int SWB = 1, int NWAVES = 8>
__device__ __forceinline__ void mmv(
    const u16* __restrict__ wpk,
    const u16* aA, const u16* aB, int strB,
    const float* __restrict__ bias,
    u16* ob) {
  const int tid = threadIdx.x;
  const int lane = tid & 63;
  const int w = tid >> 6;
  const int l15 = lane & 15;
  const int g = lane >> 4;
  if (NWAVES == 8 || w < NWAVES) {
    f32x4_t acc[4];
#pragma unroll
    for (int mt = 0; mt < 4; ++mt) acc[mt] = (f32x4_t){0.f, 0.f, 0.f, 0.f};
    __builtin_amdgcn_s_setprio(1);
#pragma unroll
    for (int kt = 0; kt < KT; ++kt) {
      half8_t af[4];
#pragma unroll
      for (int mt = 0; mt < 4; ++mt) {
        const int row = mt * 16 + l15;
        const u16* p;
        if (kt < SPLITKT) {
          p = aA + row * 128 + SWZ(row, kt * 4 + g) * 8;
        } else if (SWB) {
          p = aB + row * 128 + SWZ(row, (kt - SPLITKT) * 4 + g) * 8;
        } else {
          p = aB + row * strB + (kt - SPLITKT) * 32 + g * 8;
        }
        af[mt] = *reinterpret_cast<const half8_t*>(p);
      }
      half8_t bf = *reinterpret_cast<const half8_t*>(wpk + ((w * KT + kt) * 64 + lane) * 8);
#pragma unroll
      for (int mt = 0; mt < 4; ++mt)
        acc[mt] = __builtin_amdgcn_mfma_f32_16x16x32_f16(bf, af[mt], acc[mt], 0, 0, 0);
    }
    __builtin_amdgcn_s_setprio(0);
    const int c0 = (w << 4) + (g << 2);   // 4-aligned output column
    f32x4_t bv = *reinterpret_cast<const f32x4_t*>(bias + c0);
#pragma unroll
    for (int mt = 0; mt < 4; ++mt) {
      const int row = (mt << 4) + l15;
      half4_t hv;
#pragma unroll
      for (int r = 0; r < 4; ++r) {
        float v = acc[mt][r] + bv[r];
        if (ACT == 1) v = geluf(v);
        hv[r] = (_Float16)v;
      }
      const int e = row * 128 + (c0 ^ ((row & 7) << 3));
      *reinterpret_cast<half4_t*>(ob + e) = hv;
    }
  }
}

// layernorm rows of src [64][128](swz) -> dst [64][128](swz), 8 threads/row
__device__ __forceinline__ void lnorm(const u16* src, u16* dst,
                                      const float* __restrict__ lw,
                                      const float* __restrict__ lb) {
  const int tid = threadIdx.x;
  int q = tid >> 3, s = tid & 7;
  float xs[16];
  float sum = 0.f, sum2 = 0.f;
#pragma unroll
  for (int c8 = 0; c8 < 2; ++c8) {
    const int gi = SWZ(q, 2 * s + c8);
    half8_t v = *reinterpret_cast<const half8_t*>(src + q * 128 + gi * 8);
#pragma unroll
    for (int j = 0; j < 8; ++j) {
      float x = (float)v[j];
      xs[c8 * 8 + j] = x; sum += x; sum2 += x * x;
    }
  }
  sum += __shfl_xor(sum, 1); sum2 += __shfl_xor(sum2, 1);
  sum += __shfl_xor(sum, 2); sum2 += __shfl_xor(sum2, 2);
  sum += __shfl_xor(sum, 4); sum2 += __shfl_xor(sum2, 4);
  float mean = sum * 0.0078125f;
  float var = sum2 * 0.0078125f - mean * mean;
  float rstd = rsqrtf(var + 1e-5f);
#pragma unroll
  for (int c8 = 0; c8 < 2; ++c8) {
    half8_t r;
#pragma unroll
    for (int j = 0; j < 8; ++j) {
      int c = s * 16 + c8 * 8 + j;
      r[j] = (_Float16)((xs[c8 * 8 + j] - mean) * rstd * lw[c] + lb[c]);
    }
    const int gi = SWZ(q, 2 * s + c8);
    *reinterpret_cast<half8_t*>(dst + q * 128 + gi * 8) = r;
  }
}

// ---------------- single prep kernel ----------------
// blk 0..255:   MEGA1 k-row (top: p8_w@f1_w1; bot: (pp_w2@(sig1.f1_ph_w))@f1_w1)
// blk 256..511: MEGA2 k-row (top: p16_w@f2_w1; bot: (sig2.f2_ph_w)@f2_w1)
// blk 512: bA   blk 513: bB
// blk 514..929: static pack (copy)     blk 930..4769: feat f16 cvt
struct PrepAllArgs {
  const float *pp_w1, *pp_w2, *p8_w, *p16_w, *f1_ph_w, *f1_gate, *f1_w1, *f1_w2;
  const float *f2_ph_w, *f2_gate, *f2_w1, *f2_w2, *h_w1, *h_w2;
  const float *p8_b, *f1_ph_b, *pp_b2, *f1_b1, *p16_b, *f2_ph_b, *f2_b1;
  const float *feat8, *feat16;
  u16 *dst;
  float *bA, *bB;
  u16 *ft8, *ft16;
};

__global__ void prep_all(PrepAllArgs a) {
  __shared__ float lds[256];
  const int blk = blockIdx.x;
  const int tid = threadIdx.x;
  if (blk < 512) {
    const int sec = blk >> 8;      // 0: MEGA1, 1: MEGA2
    const int k = blk & 255;
    float* Arow = lds;             // [128]
    if (sec == 0) {
      if (k < 128) {
        if (tid < 128) Arow[tid] = a.p8_w[k * 128 + tid];
      } else {
        float* prow = lds + 128;
        if (tid < 128) prow[tid] = a.pp_w2[(k - 128) * 128 + tid];
        __syncthreads();
        if (tid < 128) {
          float sig = __builtin_amdgcn_rcpf(1.f + __expf(-a.f1_gate[tid]));
          float acc = 0.f;
          for (int r = 0; r < 128; ++r) acc += prow[r] * a.f1_ph_w[r * 128 + tid];
          Arow[tid] = acc * sig;
        }
      }
    } else {
      if (k < 128) {
        if (tid < 128) Arow[tid] = a.p16_w[k * 128 + tid];
      } else {
        if (tid < 128) {
          float sig = __builtin_amdgcn_rcpf(1.f + __expf(-a.f2_gate[tid]));
          Arow[tid] = a.f2_ph_w[(k - 128) * 128 + tid] * sig;
        }
      }
    }
    __syncthreads();
    const float* W1 = (sec == 0) ? a.f1_w1 : a.f2_w1;
    float acc = 0.f;
    for (int m = 0; m < 128; ++m) acc += Arow[m] * W1[m * 256 + tid];
    const int kt = k >> 5, hi = (k >> 3) & 3, j = k & 7;
    const int nt = tid >> 4, lo = tid & 15;
    const int base = (sec == 0) ? PW_MEGA1 : PW_MEGA2;
    a.dst[base + (((nt * 8 + kt) * 64 + hi * 16 + lo) << 3) + j] = tohalf(acc);
  } else if (blk == 512) {
    float* u = lds;
    if (tid < 128) {
      float sig = __builtin_amdgcn_rcpf(1.f + __expf(-a.f1_gate[tid]));
      float acc = 0.f;
      for (int r = 0; r < 128; ++r) acc += a.pp_b2[r] * a.f1_ph_w[r * 128 + tid];
      u[tid] = a.p8_b[tid] + sig * a.f1_ph_b[tid] + sig * acc;
    }
    __syncthreads();
    float acc = a.f1_b1[tid];
    for (int m = 0; m < 128; ++m) acc += u[m] * a.f1_w1[m * 256 + tid];
    a.bA[tid] = acc;
  } else if (blk == 513) {
    float acc = a.f2_b1[tid];
    for (int m = 0; m < 128; ++m) {
      float sig = __builtin_amdgcn_rcpf(1.f + __expf(-a.f2_gate[m]));
      acc += (a.p16_b[m] + sig * a.f2_ph_b[m]) * a.f2_w1[m * 256 + tid];
    }
    a.bB[tid] = acc;
  } else if (blk < 930) {
    // static pack: virtual index over 5 copy sections (106496 elements)
    const int vi = (blk - 514) * 256 + tid;
    const int vb[6] = {0, 12288, 45056, 77824, 98304, 106496};
    const int KTs[5] = {3, 8, 8, 5, 4};
    const int Ks[5]  = {75, 256, 256, 156, 128};
    const int Ns[5]  = {128, 128, 128, 128, 64};
    const int pw[5]  = {PW_PP1, PW_S8, PW_S15, PW_HW1, PW_HW2};
    int s = 0;
    while (vi >= vb[s + 1]) ++s;
    const int rem = vi - vb[s];
    const int e = rem & 511, lane = e >> 3, j = e & 7;
    const int ntkt = rem >> 9;
    const int kt = ntkt % KTs[s], nt = ntkt / KTs[s];
    const int k = kt * 32 + ((lane >> 4) << 3) + j;
    const int col = (nt << 4) + (lane & 15);
    const float* src = (s == 0) ? a.pp_w1 : (s == 1) ? a.f1_w2
                     : (s == 2) ? a.f2_w2 : (s == 3) ? a.h_w1 : a.h_w2;
    float v = (k < Ks[s]) ? src[k * Ns[s] + col] : 0.f;
    a.dst[pw[s] + rem] = tohalf(v);
  } else {
    const int tot8 = 2 * 128 * H8 * W8;
    const int i = (blk - 930) * 256 + tid;
    if (i < tot8) {
      int x = i % W8;
      int t = i / W8;
      int y = t % H8; t /= H8;
      int c = t % 128;
      int b = t / 128;
      a.ft8[((b * H8 + y) * W8 + x) * 128 + c] = tohalf(a.feat8[i]);
    } else {
      int i2 = i - tot8;
      int x = i2 % W16;
      int t = i2 / W16;
      int y = t % H16; t /= H16;
      int c = t % 128;
      int b = t / 128;
      a.ft16[((b * H16 + y) * W16 + x) * 128 + c] = tohalf(a.feat16[i2]);
    }
  }
}

// ---------------- main fused kernel (11 phases, 4 swizzled LDS buffers) ------
struct KParams {
  const float *img, *coarse_flow, *qc;
  const u16 *wpk, *ft8, *ft16;
  const float *bA, *bB;
  u16* peg;      // [2048][64][40] pe/coarse staging (global, L3-resident)
  float* cbg;    // [2048][64][2]
  const float *pp_b1;
  const float *f1_b2, *f1_ln_w, *f1_ln_b;
  const float *f2_b2, *f2_ln_w, *f2_ln_b;
  const float *h_b1, *h_b2, *h_w3, *h_b3;
  float* out;
};

__global__ __launch_bounds__(NT, 2) void ifd_mfma(KParams P) {
  __shared__ __align__(16) u16 smem[4 * MB * SAB];   // 65536 B exactly -> 2 blocks/CU
  u16* ab0 = smem;
  u16* ab1 = smem + MB * SAB;
  u16* tb  = smem + 2 * MB * SAB;
  u16* hb  = smem + 3 * MB * SAB;

  const int tid = threadIdx.x;
  const int m0 = blockIdx.x * MB;
  u16* pegB = P.peg + blockIdx.x * (MB * SPE);
  float* cbgB = P.cbg + blockIdx.x * (MB * 2);

  // ---- Ph1: patches -> ab0[0..95](swz); pe/coarse -> peg + cbg ----
  {
    const int q = tid >> 3, sub = tid & 7;
    const int m = m0 + q, b = m >> 16;
    const float qx = P.qc[2 * m], qy = P.qc[2 * m + 1];
    const float* imgb = P.img + b * 3 * (IMG_H * IMG_W);
#pragma unroll
    for (int j = 0; j < 12; ++j) {
      const int c = sub * 12 + j;
      u16 val = 0;
      if (c < 75) {
        int p = c / 3, ch = c - p * 3;
        int iy = p / 5, ix = p - iy * 5;
        val = tohalf(bilin_plane(imgb + ch * (IMG_H * IMG_W), IMG_W, IMG_H,
                                 qx + (float)(ix - 2), qy + (float)(iy - 2)));
      }
      ab0[q * 128 + (c ^ ((q & 7) << 3))] = val;
    }
  }
  if (tid < 128) {  // pe via angle doubling
    const int q = tid >> 1, dim = tid & 1;
    const int m = m0 + q;
    const float qv = P.qc[2 * m + dim];
    const float q8 = qv * 0.125f;
    const float loc = (q8 - rintf(q8)) * 2.f;
    pegB[q * SPE + dim] = tohalf(loc);
    const float th = loc * 3.14159265358979323846f;
    float s = __sinf(th), c = __cosf(th);
    const int base = q * SPE + 2 + dim * 12;
#pragma unroll
    for (int bnd = 0; bnd < 6; ++bnd) {
      pegB[base + bnd] = tohalf(s);
      pegB[base + 6 + bnd] = tohalf(c);
      float s2 = 2.f * s * c;
      c = fmaf(-2.f * s, s, 1.f);
      s = s2;
    }
  } else if (tid < 256) {  // coarse
    const int t2 = tid - 128, q = t2 >> 1, o = t2 & 1;
    const int m = m0 + q, b = m >> 16;
    const float qx = P.qc[2 * m], qy = P.qc[2 * m + 1];
    const float x8 = qx * (63.f / 511.f), y8 = qy * (47.f / 383.f);
    const float cv = 8.f * bilin_plane(P.coarse_flow + (b * 2 + o) * (H8 * W8),
                                       W8, H8, x8, y8);
    pegB[q * SPE + 26 + o] = tohalf(cv);
    cbgB[q * 2 + o] = cv;
  } else if (tid < 384) {  // zero peg cols 28..31 (kt4 pad)
    const int t2 = tid - 256, q = t2 >> 1, pr = t2 & 1;
    *reinterpret_cast<unsigned int*>(pegB + q * SPE + 28 + 2 * pr) = 0u;
  }
  __syncthreads();

  // ---- Ph2: S1 (ab0 -> ab1) || samp8 -> hb ----
  mmv<3, 3, 1>(P.wpk + PW_PP1, ab0, ab0, 128, P.pp_b1, ab1);
  for (int i = tid; i < MB * 16; i += NT) {
    int q = i >> 4, i16 = i & 15;
    int m = m0 + q, b = m >> 16;
    float x = P.qc[2 * m] * (63.f / 511.f), y = P.qc[2 * m + 1] * (47.f / 383.f);
    featSample(P.ft8 + b * (H8 * W8 * 128), W8, H8, x, y, hb + q * 128,
               i16, SWZ(q, i16));
  }
  __syncthreads();

  // ---- Ph3: MEGA1: wide = gelu([samp8(hb) | t1(ab1)] @ WA + bA) -> [ab0 | tb] ----
  mmv<8, 4, 1>(P.wpk + PW_MEGA1, hb, ab1, 128, P.bA, ab0);
  mmv<8, 4, 1>(P.wpk + PW_MEGA1 + 32768, hb, ab1, 128, P.bA + 128, tb);
  __syncthreads();

  // ---- Ph4: S8: [ab0 | tb] @ f1_w2 + f1_b2 -> ab1 ----
  mmv<8, 4, 0>(P.wpk + PW_S8, ab0, tb, 128, P.f1_b2, ab1);
  __syncthreads();

  // ---- Ph5: LN1 (ab1 -> hb) || samp16 -> ab0 ----
  lnorm(ab1, hb, P.f1_ln_w, P.f1_ln_b);
  for (int i = tid; i < MB * 16; i += NT) {
    int q = i >> 4, i16 = i & 15;
    int m = m0 + q, b = m >> 16;
    float x = P.qc[2 * m] * (31.f / 511.f), y = P.qc[2 * m + 1] * (23.f / 383.f);
    featSample(P.ft16 + b * (H16 * W16 * 128), W16, H16, x, y, ab0 + q * 128,
               i16, SWZ(q, i16));
  }
  __syncthreads();

  // ---- Ph6: MEGA2: wide2 = gelu([samp16(ab0) | h2(hb)] @ WB + bB) -> [ab1 | tb] ----
  mmv<8, 4, 1>(P.wpk + PW_MEGA2, ab0, hb, 128, P.bB, ab1);
  mmv<8, 4, 1>(P.wpk + PW_MEGA2 + 32768, ab0, hb, 128, P.bB + 128, tb);
  __syncthreads();

  // ---- Ph7: S15: [ab1 | tb] @ f2_w2 + f2_b2 -> ab0 ----
  mmv<8, 4, 0>(P.wpk + PW_S15, ab1, tb, 128, P.f2_b2, ab0);
  __syncthreads();

  // ---- Ph8: LN2: ab0 -> hb ----
  lnorm(ab0, hb, P.f2_ln_w, P.f2_ln_b);
  __syncthreads();

  // ---- Ph9: S18: gelu([hb | peg] @ h_w1 + h_b1) -> ab1  (K=160, peg unswizzled) ----
  mmv<5, 4, 1, 0>(P.wpk + PW_HW1, hb, pegB, SPE, P.h_b1, ab1);
  __syncthreads();

  // ---- Ph10: S19: gelu(ab1 @ h_w2 + h_b2) -> ab0[0..63]  (waves 0-3) ----
  mmv<4, 4, 1, 1, 4>(P.wpk + PW_HW2, ab1, ab1, 128, P.h_b2, ab0);
  __syncthreads();

  // ---- Ph11: S20: out = coarse + (g @ h_w3 + h_b3) ----
  if (tid < 2 * MB) {
    int q = tid >> 1, o = tid & 1;
    float acc = P.h_b3[o];
    const u16* rp = ab0 + q * 128;
#pragma unroll
    for (int c8 = 0; c8 < 8; ++c8) {
      half8_t v = *reinterpret_cast<const half8_t*>(rp + SWZ(q, c8) * 8);
#pragma unroll
      for (int j = 0; j < 8; ++j) acc += (float)v[j] * P.h_w3[(c8 * 8 + j) * 2 + o];
    }
    P.out[(m0 + q) * 2 + o] = cbgB[q * 2 + o] + acc;
  }
}

extern "C" void kernel_launch(void* const* d_in, const int* in_sizes, int n_in,
                              void* d_out, int out_size, void* d_ws, size_t ws_size,
                              hipStream_t stream) {
  u16* wp = (u16*)d_ws;
  float* fbase = (float*)(wp + F32_OFF);
  float* bA = fbase;
  float* bB = fbase + 256;
  u16* peg = wp + PEG_OFF;
  float* cbg = (float*)(wp + CBG_OFF);

  PrepAllArgs pra;
  pra.pp_w1 = (const float*)d_in[5];
  pra.pp_w2 = (const float*)d_in[7];
  pra.p8_w  = (const float*)d_in[9];
  pra.p16_w = (const float*)d_in[11];
  pra.f1_ph_w = (const float*)d_in[13];
  pra.f1_gate = (const float*)d_in[15];
  pra.f1_w1 = (const float*)d_in[16];
  pra.f1_w2 = (const float*)d_in[18];
  pra.f2_ph_w = (const float*)d_in[22];
  pra.f2_gate = (const float*)d_in[24];
  pra.f2_w1 = (const float*)d_in[25];
  pra.f2_w2 = (const float*)d_in[27];
  pra.h_w1  = (const float*)d_in[31];
  pra.h_w2  = (const float*)d_in[33];
  pra.p8_b  = (const float*)d_in[10];
  pra.f1_ph_b = (const float*)d_in[14];
  pra.pp_b2 = (const float*)d_in[8];
  pra.f1_b1 = (const float*)d_in[17];
  pra.p16_b = (const float*)d_in[12];
  pra.f2_ph_b = (const float*)d_in[23];
  pra.f2_b1 = (const float*)d_in[26];
  pra.feat8 = (const float*)d_in[1];
  pra.feat16 = (const float*)d_in[2];
  pra.dst = wp;
  pra.bA = bA; pra.bB = bB;
  pra.ft8 = wp + FT8_OFF;
  pra.ft16 = wp + FT16_OFF;
  prep_all<<<4770, 256, 0, stream>>>(pra);

  KParams P;
  P.img = (const float*)d_in[0];
  P.coarse_flow = (const float*)d_in[3];
  P.qc = (const float*)d_in[4];
  P.wpk = wp; P.ft8 = wp + FT8_OFF; P.ft16 = wp + FT16_OFF;
  P.bA = bA; P.bB = bB;
  P.peg = peg; P.cbg = cbg;
  P.pp_b1 = (const float*)d_in[6];
  P.f1_b2 = (const float*)d_in[19];
  P.f1_ln_w = (const float*)d_in[20]; P.f1_ln_b = (const float*)d_in[21];
  P.f2_b2 = (const float*)d_in[28];
  P.f2_ln_w = (const float*)d_in[29]; P.f2_ln_b = (const float*)d_in[30];
  P.h_b1 = (const float*)d_in[32]; P.h_b2 = (const float*)d_in[34];
  P.h_w3 = (const float*)d_in[35]; P.h_b3 = (const float*)d_in[36];
  P.out = (float*)d_out;

  ifd_mfma<<<MTOT / MB, NT, 0, stream>>>(P);
}